// Round 5
// baseline (563.821 us; speedup 1.0000x reference)
//
#include <hip/hip_runtime.h>

#define Nn 100000
#define Ee 1600000
#define IND 256
#define HD 128
#define NCLS 40
#define NBLK 391   // ceil(Nn/256)

typedef _Float16 f16;
typedef f16 f16x8 __attribute__((ext_vector_type(8)));
typedef f16 f16x4 __attribute__((ext_vector_type(4)));
typedef float f32x4 __attribute__((ext_vector_type(4)));

// ---------------------------------------------------------------------------
// CSR build: histogram -> exclusive scan -> bucket scatter.
// ---------------------------------------------------------------------------
extern "C" __global__ void __launch_bounds__(256)
k_hist(const int* __restrict__ ei, int* __restrict__ counts) {
    int e = blockIdx.x * 256 + threadIdx.x;
    if (e < Ee) atomicAdd(&counts[ei[Ee + e]], 1);
}

extern "C" __global__ void __launch_bounds__(256)
k_scan1(const int* __restrict__ counts, int* __restrict__ bsum) {
    __shared__ int s[256];
    int t = threadIdx.x;
    int i = blockIdx.x * 256 + t;
    s[t] = (i < Nn) ? counts[i] : 0;
    __syncthreads();
    for (int d = 128; d > 0; d >>= 1) {
        if (t < d) s[t] += s[t + d];
        __syncthreads();
    }
    if (t == 0) bsum[blockIdx.x] = s[0];
}

extern "C" __global__ void __launch_bounds__(512)
k_scan2(int* __restrict__ bsum) {
    __shared__ int s[512];
    int t = threadIdx.x;
    int v = (t < NBLK) ? bsum[t] : 0;
    s[t] = v;
    __syncthreads();
    for (int d = 1; d < 512; d <<= 1) {
        int x = (t >= d) ? s[t - d] : 0;
        __syncthreads();
        s[t] += x;
        __syncthreads();
    }
    if (t < NBLK) bsum[t] = s[t] - v;
}

extern "C" __global__ void __launch_bounds__(256)
k_scan3(const int* __restrict__ counts, const int* __restrict__ bsum,
        int* __restrict__ offsets) {
    __shared__ int s[256];
    int t = threadIdx.x;
    int i = blockIdx.x * 256 + t;
    int v = (i < Nn) ? counts[i] : 0;
    s[t] = v;
    __syncthreads();
    for (int d = 1; d < 256; d <<= 1) {
        int x = (t >= d) ? s[t - d] : 0;
        __syncthreads();
        s[t] += x;
        __syncthreads();
    }
    if (i < Nn) offsets[i] = bsum[blockIdx.x] + s[t] - v;
    if (i == 0) offsets[Nn] = Ee;
}

extern "C" __global__ void __launch_bounds__(256)
k_scatter(const int* __restrict__ ei, const int* __restrict__ offsets,
          int* __restrict__ pos, int* __restrict__ bucket) {
    int e = blockIdx.x * 256 + threadIdx.x;
    if (e >= Ee) return;
    int dst = ei[Ee + e];
    int p = offsets[dst] + atomicAdd(&pos[dst], 1);
    bucket[p] = ei[e];
}

// ---------------------------------------------------------------------------
// emb fp32 -> f16 streaming convert (8 elems/thread).
// ---------------------------------------------------------------------------
extern "C" __global__ void __launch_bounds__(256)
k_embh(const float* __restrict__ emb, f16* __restrict__ embh) {
    int idx = (blockIdx.x * 256 + threadIdx.x) * 8;
    float4 a = *(const float4*)(emb + idx);
    float4 b = *(const float4*)(emb + idx + 4);
    f16x8 h;
    h[0] = (f16)a.x; h[1] = (f16)a.y; h[2] = (f16)a.z; h[3] = (f16)a.w;
    h[4] = (f16)b.x; h[5] = (f16)b.y; h[6] = (f16)b.z; h[7] = (f16)b.w;
    *(f16x8*)(embh + idx) = h;
}

// ---------------------------------------------------------------------------
// Fused weight pack: all 5 MLP weights + zero-padded wc into f16 B-frag layout
//   P[((ft*KT+kt)*64+L)*8+j] = W[kt*32+(L>>4)*8+j][ft*16+(L&15)]
// ---------------------------------------------------------------------------
extern "C" __global__ void __launch_bounds__(256)
k_wpack(const float* __restrict__ wx1, const float* __restrict__ wx2,
        const float* __restrict__ wa1, const float* __restrict__ wa2,
        const float* __restrict__ ww1, const float* __restrict__ wc,
        f16* __restrict__ wp) {
    int idx = blockIdx.x * 256 + threadIdx.x;
    const float* W;
    int K, base;
    if (idx < 32768)       { W = wx1; K = 256; base = 0; }
    else if (idx < 49152)  { W = wx2; K = 128; base = 32768; }
    else if (idx < 65536)  { W = wa1; K = 128; base = 49152; }
    else if (idx < 81920)  { W = wa2; K = 128; base = 65536; }
    else if (idx < 114688) { W = ww1; K = 256; base = 81920; }
    else {
        int local = idx - 114688;   // wc padded to 48 cols, KT=4
        int j = local & 7;
        int L = (local >> 3) & 63;
        int kt = (local >> 9) & 3;
        int ft = local / 2048;
        int k = kt * 32 + (L >> 4) * 8 + j;
        int n = ft * 16 + (L & 15);
        wp[idx] = (n < NCLS) ? (f16)wc[k * NCLS + n] : (f16)0.f;
        return;
    }
    int local = idx - base;
    int KT = K >> 5;
    int j = local & 7;
    int L = (local >> 3) & 63;
    int kt = (local >> 9) % KT;
    int ft = local / (512 * KT);
    int k = kt * 32 + (L >> 4) * 8 + j;
    int n = ft * 16 + (L & 15);
    wp[idx] = (f16)W[k * HD + n];
}

// ---------------------------------------------------------------------------
// Gather-mean (f16 source): one wave per node. 16 lanes x 8 cols (16B loads),
// 4 edge-groups, unroll 2 -> 8 emb rows in flight per wave. Output written in
// MFMA A-fragment packed layout.
// ---------------------------------------------------------------------------
extern "C" __global__ void __launch_bounds__(256)
k_gather(const int* __restrict__ offsets, const int* __restrict__ bucket,
         const f16* __restrict__ embh, f16* __restrict__ harawp) {
    int t = threadIdx.x;
    int lane = t & 63;
    int node = blockIdx.x * 4 + (t >> 6);
    int colg = lane & 15;
    int eg = lane >> 4;

    int beg = offsets[node];
    int end = offsets[node + 1];
    float s[8];
#pragma unroll
    for (int j = 0; j < 8; j++) s[j] = 0.f;

    int i = beg + eg;
    for (; i + 4 < end; i += 8) {
        int r0 = bucket[i];
        int r1 = bucket[i + 4];
        f16x8 a = *(const f16x8*)(embh + (size_t)r0 * HD + colg * 8);
        f16x8 b = *(const f16x8*)(embh + (size_t)r1 * HD + colg * 8);
#pragma unroll
        for (int j = 0; j < 8; j++) s[j] += (float)a[j] + (float)b[j];
    }
    for (; i < end; i += 4) {
        int r0 = bucket[i];
        f16x8 a = *(const f16x8*)(embh + (size_t)r0 * HD + colg * 8);
#pragma unroll
        for (int j = 0; j < 8; j++) s[j] += (float)a[j];
    }
#pragma unroll
    for (int j = 0; j < 8; j++) s[j] += __shfl_down(s[j], 32);
#pragma unroll
    for (int j = 0; j < 8; j++) s[j] += __shfl_down(s[j], 16);

    if (lane < 16) {
        float inv = 1.0f / fmaxf((float)(end - beg), 1.0f);
        f16x8 h;
#pragma unroll
        for (int j = 0; j < 8; j++) h[j] = (f16)(s[j] * inv);
        int nt = node >> 4, m = node & 15;
        *(f16x8*)(harawp +
                  ((nt * 4 + (colg >> 2)) * 64 + m + 16 * (colg & 3)) * 8) = h;
    }
}

// ---------------------------------------------------------------------------
// Fused MLP, all-MFMA. 64 nodes/block, 512 threads (8 waves):
// mt = wid>>1 (node 16-tile 0..3), fh = wid&1 (feature half).
// LDS 48KB (shr + hxp + hap) -> 3 blocks/CU = 24 waves/CU.
// Logits staged in LDS, stored as one contiguous 10KB block (fixes 5.7x
// write amplification seen in R4: WRITE_SIZE 90.6MB vs 16MB ideal).
// ---------------------------------------------------------------------------
extern "C" __global__ void __launch_bounds__(512, 6)
linkx_mlp(const float* __restrict__ x, const f16* __restrict__ harawp,
          const f16* __restrict__ wx1p, const float* __restrict__ bx1,
          const f16* __restrict__ wx2p, const float* __restrict__ bx2,
          const f16* __restrict__ wa1p, const float* __restrict__ ba1,
          const f16* __restrict__ wa2p, const float* __restrict__ ba2,
          const f16* __restrict__ ww1p, const float* __restrict__ bw1,
          const f16* __restrict__ wcp, const float* __restrict__ bc,
          float* __restrict__ out) {
    __shared__ __align__(16) f16 shr[8192];   // t1p / t2p / h2p (16KB shared)
    __shared__ __align__(16) f16 hxp[8192];   // hx packed; later logit staging
    __shared__ __align__(16) f16 hap[8192];   // ha packed

    const int t = threadIdx.x;
    const int node0 = blockIdx.x * 64;
    const int lane = t & 63;
    const int wid = t >> 6;
    const int mt = wid >> 1;
    const int fh = wid & 1;

    f32x4 acc[4];
    float rreg[4][4];   // hx+ha residual, same C-tile as acc

#define INIT_ACC(BIAS)                                                    \
    _Pragma("unroll")                                                     \
    for (int q = 0; q < 4; q++) {                                         \
        float bv = (BIAS)[(fh * 4 + q) * 16 + (lane & 15)];               \
        acc[q][0] = bv; acc[q][1] = bv; acc[q][2] = bv; acc[q][3] = bv;   \
    }

#define GEMM_K128(APACK, BP)                                                  \
    _Pragma("unroll")                                                         \
    for (int kt = 0; kt < 4; kt++) {                                          \
        f16x8 a = *(const f16x8*)((APACK) + ((mt * 4 + kt) * 64 + lane) * 8); \
        _Pragma("unroll")                                                     \
        for (int q = 0; q < 4; q++) {                                         \
            f16x8 b = *(const f16x8*)((BP) + (((fh*4+q)*4 + kt)*64 + lane)*8);\
            acc[q] = __builtin_amdgcn_mfma_f32_16x16x32_f16(a, b, acc[q], 0, 0, 0); \
        }                                                                     \
    }

    // MODE 0: relu; 1: no relu, rreg=v; 2: no relu, rreg+=v;
    // 3: v=relu(relu(v)+rreg)
#define EPILOGUE(MODE, PDST)                                                  \
    _Pragma("unroll")                                                         \
    for (int q = 0; q < 4; q++) {                                             \
        int f = (fh * 4 + q) * 16 + (lane & 15);                              \
        int kt2 = f >> 5, q2 = (f >> 3) & 3, j2 = f & 7;                      \
        _Pragma("unroll")                                                     \
        for (int r = 0; r < 4; r++) {                                         \
            int n = (lane >> 4) * 4 + r;                                      \
            float v = acc[q][r];                                              \
            if (MODE == 0) v = fmaxf(v, 0.f);                                 \
            if (MODE == 1) rreg[q][r] = v;                                    \
            if (MODE == 2) rreg[q][r] += v;                                   \
            if (MODE == 3) v = fmaxf(fmaxf(v, 0.f) + rreg[q][r], 0.f);        \
            (PDST)[((mt * 4 + kt2) * 64 + n + 16 * q2) * 8 + j2] = (f16)v;    \
        }                                                                     \
    }

    // step2: t1 = relu(x @ wx1 + bx1), K=256; A from global x (fp32->f16)
    INIT_ACC(bx1)
#pragma unroll
    for (int kt = 0; kt < 8; kt++) {
        int row = node0 + mt * 16 + (lane & 15);
        if (row >= Nn) row = Nn - 1;   // tail block clamp (results discarded)
        const float* xr = x + (size_t)row * IND + kt * 32 + (lane >> 4) * 8;
        float4 u0 = *(const float4*)(xr);
        float4 u1 = *(const float4*)(xr + 4);
        f16x8 a;
        a[0] = (f16)u0.x; a[1] = (f16)u0.y; a[2] = (f16)u0.z; a[3] = (f16)u0.w;
        a[4] = (f16)u1.x; a[5] = (f16)u1.y; a[6] = (f16)u1.z; a[7] = (f16)u1.w;
#pragma unroll
        for (int q = 0; q < 4; q++) {
            f16x8 b = *(const f16x8*)(wx1p + (((fh*4+q)*8 + kt)*64 + lane)*8);
            acc[q] = __builtin_amdgcn_mfma_f32_16x16x32_f16(a, b, acc[q], 0, 0, 0);
        }
    }
    EPILOGUE(0, shr)          // t1p
    __syncthreads();

    // step3: hx = t1 @ wx2 + bx2 -> hxp, rreg = hx
    INIT_ACC(bx2)
    GEMM_K128(shr, wx2p)
    EPILOGUE(1, hxp)
    __syncthreads();

    // step5: t2 = relu(haraw @ wa1 + ba1); A direct from global packed f16
    INIT_ACC(ba1)
    {
        int ntb = (node0 >> 4) + mt;
#pragma unroll
        for (int kt = 0; kt < 4; kt++) {
            f16x8 a = *(const f16x8*)(harawp + ((ntb * 4 + kt) * 64 + lane) * 8);
#pragma unroll
            for (int q = 0; q < 4; q++) {
                f16x8 b = *(const f16x8*)(wa1p + (((fh*4+q)*4 + kt)*64 + lane)*8);
                acc[q] = __builtin_amdgcn_mfma_f32_16x16x32_f16(a, b, acc[q], 0, 0, 0);
            }
        }
    }
    EPILOGUE(0, shr)          // t2p
    __syncthreads();

    // step6: ha = t2 @ wa2 + ba2 -> hap, rreg += ha
    INIT_ACC(ba2)
    GEMM_K128(shr, wa2p)
    EPILOGUE(2, hap)
    __syncthreads();

    // step7+8: h2 = relu(relu([hx|ha] @ ww1 + bw1) + hx + ha) -> h2p
    INIT_ACC(bw1)
#pragma unroll
    for (int kt = 0; kt < 8; kt++) {
        const f16* ap = (kt < 4) ? (hxp + ((mt * 4 + kt) * 64 + lane) * 8)
                                 : (hap + ((mt * 4 + (kt - 4)) * 64 + lane) * 8);
        f16x8 a = *(const f16x8*)ap;
#pragma unroll
        for (int q = 0; q < 4; q++) {
            f16x8 b = *(const f16x8*)(ww1p + (((fh*4+q)*8 + kt)*64 + lane)*8);
            acc[q] = __builtin_amdgcn_mfma_f32_16x16x32_f16(a, b, acc[q], 0, 0, 0);
        }
    }
    EPILOGUE(3, shr)          // h2p
    __syncthreads();

    // step9: logits = h2 @ wc + bc -> LDS staging (hxp region, dead)
    float* lf = (float*)hxp;   // 64*40 floats = 10KB <= 16KB
    {
        int nft = (fh == 0) ? 2 : 1;
#pragma unroll 2
        for (int ii = 0; ii < nft; ii++) {
            int ft = (ii == 0) ? fh : 2;
            int f = ft * 16 + (lane & 15);
            f32x4 c;
            float bv = (f < NCLS) ? bc[f] : 0.f;
            c[0] = bv; c[1] = bv; c[2] = bv; c[3] = bv;
#pragma unroll
            for (int kt = 0; kt < 4; kt++) {
                f16x8 a = *(const f16x8*)(shr + ((mt * 4 + kt) * 64 + lane) * 8);
                f16x8 b = *(const f16x8*)(wcp + ((ft * 4 + kt) * 64 + lane) * 8);
                c = __builtin_amdgcn_mfma_f32_16x16x32_f16(a, b, c, 0, 0, 0);
            }
            if (f < NCLS) {
#pragma unroll
                for (int r = 0; r < 4; r++) {
                    int n = mt * 16 + (lane >> 4) * 4 + r;
                    lf[n * NCLS + f] = c[r];
                }
            }
        }
    }
    __syncthreads();

    // coalesced logit store: one contiguous block of 64*40 floats
    {
        int nvalid = Nn - node0;               // 64 or 32 (tail)
        if (nvalid > 64) nvalid = 64;
        int nf4 = (nvalid * NCLS) >> 2;        // multiples of 4
        float4* dst = (float4*)(out + (size_t)node0 * NCLS);
        const float4* src = (const float4*)lf;
        for (int idx = t; idx < nf4; idx += 512) dst[idx] = src[idx];
    }
}

extern "C" void kernel_launch(void* const* d_in, const int* in_sizes, int n_in,
                              void* d_out, int out_size, void* d_ws, size_t ws_size,
                              hipStream_t stream) {
    const float* x   = (const float*)d_in[0];
    const int*   ei  = (const int*)d_in[1];
    const float* emb = (const float*)d_in[2];
    const float* wx1 = (const float*)d_in[3];
    const float* bx1 = (const float*)d_in[4];
    const float* wx2 = (const float*)d_in[5];
    const float* bx2 = (const float*)d_in[6];
    const float* wa1 = (const float*)d_in[7];
    const float* ba1 = (const float*)d_in[8];
    const float* wa2 = (const float*)d_in[9];
    const float* ba2 = (const float*)d_in[10];
    const float* ww1 = (const float*)d_in[11];
    const float* bw1 = (const float*)d_in[12];
    const float* wc  = (const float*)d_in[13];
    const float* bc  = (const float*)d_in[14];
    float* out = (float*)d_out;

    int* ws = (int*)d_ws;
    int* counts  = ws;                 // [Nn]
    int* pos     = ws + Nn;            // [Nn]
    int* offsets = ws + 2 * Nn;        // [Nn+1]
    int* bsum    = ws + 3 * Nn + 16;   // [NBLK]
    int* bucket  = ws + 3 * Nn + 512;  // [Ee]
    f16* wp      = (f16*)(ws + 3 * Nn + 512 + Ee);  // 120832 f16 used
    f16* wx1p = wp;                 // 32768
    f16* wx2p = wp + 32768;         // 16384
    f16* wa1p = wp + 49152;         // 16384
    f16* wa2p = wp + 65536;         // 16384
    f16* ww1p = wp + 81920;         // 32768
    f16* wcp  = wp + 114688;        // 6144
    f16* harawp = wp + 131072;             // [Nn*HD + 4096] (pad for tail tiles)
    f16* embh   = harawp + Nn * HD + 4096; // [Nn*HD]

    hipMemsetAsync(ws, 0, (size_t)(2 * Nn) * sizeof(int), stream);

    k_hist<<<Ee / 256, 256, 0, stream>>>(ei, counts);
    k_scan1<<<NBLK, 256, 0, stream>>>(counts, bsum);
    k_scan2<<<1, 512, 0, stream>>>(bsum);
    k_scan3<<<NBLK, 256, 0, stream>>>(counts, bsum, offsets);
    k_scatter<<<Ee / 256, 256, 0, stream>>>(ei, offsets, pos, bucket);
    k_embh<<<(Nn * HD) / (256 * 8), 256, 0, stream>>>(emb, embh);
    k_wpack<<<472, 256, 0, stream>>>(wx1, wx2, wa1, wa2, ww1, wc, wp);
    k_gather<<<Nn / 4, 256, 0, stream>>>(offsets, bucket, embh, harawp);

    linkx_mlp<<<(Nn + 63) / 64, 512, 0, stream>>>(x, harawp,
                                                  wx1p, bx1, wx2p, bx2,
                                                  wa1p, ba1, wa2p, ba2,
                                                  ww1p, bw1, wcp, bc, out);
}